// Round 9
// baseline (152.457 us; speedup 1.0000x reference)
//
#include <hip/hip_runtime.h>
#include <hip/hip_bf16.h>
#include <stdint.h>

#define NHEADS 12
#define HSZ 64
#define BATCH 8
#define SEQ 1024
#define DIN 1024
#define NPROJ 1536   // NHEADS*HSZ*2
#define MTOK 8192    // BATCH*SEQ
#define NEGV 1e12f

typedef float  f32x4  __attribute__((ext_vector_type(4)));
typedef __bf16 bf16x8 __attribute__((ext_vector_type(8)));

__device__ __forceinline__ ushort f2bf(float x) {
  union { float f; uint32_t u; } v; v.f = x;
  uint32_t r = v.u + 0x7FFFu + ((v.u >> 16) & 1u);
  return (ushort)(r >> 16);
}

__device__ __forceinline__ void async16(const void* g, void* l) {
  __builtin_amdgcn_global_load_lds(
      (const __attribute__((address_space(1))) uint32_t*)g,
      (__attribute__((address_space(3))) uint32_t*)l,
      16, 0, 0);
}

// tile-pair enumerations (8x8 tile grid), packed (mi<<4)|ni
// LOWER: mi > ni  (fully causal-masked, 28)  — handled by fill blocks
__device__ const uint8_t LOWER28[28] = {
  0x10, 0x20,0x21, 0x30,0x31,0x32, 0x40,0x41,0x42,0x43,
  0x50,0x51,0x52,0x53,0x54, 0x60,0x61,0x62,0x63,0x64,0x65,
  0x70,0x71,0x72,0x73,0x74,0x75,0x76 };
// UPPER: mi <= ni (needs MFMA, 36) — handled by k_logits
__device__ const uint8_t UPPER36[36] = {
  0x00,0x01,0x02,0x03,0x04,0x05,0x06,0x07,
  0x11,0x12,0x13,0x14,0x15,0x16,0x17,
  0x22,0x23,0x24,0x25,0x26,0x27,
  0x33,0x34,0x35,0x36,0x37,
  0x44,0x45,0x46,0x47,
  0x55,0x56,0x57,
  0x66,0x67,
  0x77 };

// ---------------- merged prep kernel ----------------
__global__ __launch_bounds__(256) void k_prep(
    const float* __restrict__ inp, const float* __restrict__ W,
    ushort* __restrict__ A16, ushort* __restrict__ Wt, float* __restrict__ tab) {
  const int blk = blockIdx.x;
  const int tid = threadIdx.x;
  if (blk < 2048) {
    const float4* in4 = (const float4*)inp;
    ushort4* out4 = (ushort4*)A16;
    const int n4 = MTOK * DIN / 4;
    int i = blk * 256 + tid;
    for (; i < n4; i += 2048 * 256) {
      float4 v = in4[i];
      ushort4 o;
      o.x = f2bf(v.x); o.y = f2bf(v.y); o.z = f2bf(v.z); o.w = f2bf(v.w);
      out4[i] = o;
    }
  } else if (blk < 2432) {
    __shared__ float tile[64][65];
    const int bb = blk - 2048;           // 384 = 24 x 16
    const int n0 = (bb % 24) * 64;
    const int k0 = (bb / 24) * 64;
    const int c  = tid & 63;
    const int r0 = (tid >> 6) * 16;
    #pragma unroll
    for (int rr = 0; rr < 16; ++rr)
      tile[r0 + rr][c] = W[(size_t)(k0 + r0 + rr) * NPROJ + n0 + c];
    __syncthreads();
    #pragma unroll
    for (int rr = 0; rr < 16; ++rr)
      Wt[(size_t)(n0 + r0 + rr) * DIN + k0 + c] = f2bf(tile[c][r0 + rr]);
  } else {
    const int t = (blk - 2432) * 256 + tid;  // 32768 total
    const int s = t >> 5, i = t & 31;
    const float p   = powf(10000.0f, (float)i / 32.0f);
    const float ang = (float)s / p;
    tab[2 * t]     = sinf(ang);
    tab[2 * t + 1] = cosf(ang);
  }
}

// ------- fused: projection GEMM + RoPE (blocks 0..767)  +
//                causal-masked output fill (blocks 768..3455) -------
// NOTE (r7/r8 lesson): do NOT interleave fill IDs with proj IDs — co-resident
// fill write-streams inflate proj's per-K-step vmcnt-drain latency and cost
// +17..24 µs. Proj-first ordering (fill backfills as proj retires) is optimal.
__global__ __launch_bounds__(256) void k_proj_fill(
    const ushort* __restrict__ A, const ushort* __restrict__ Bt,
    const float* __restrict__ bias, const float* __restrict__ tab,
    ushort* __restrict__ Qb, ushort* __restrict__ Kb,
    const int* __restrict__ mask, float* __restrict__ out) {
  __shared__ __align__(16) ushort As[128 * 64];
  __shared__ __align__(16) ushort Bs[128 * 64];
  const int tid  = threadIdx.x;

  if (blockIdx.x >= 768) {
    // ---- causal fill path: one 128x128 tile per block, pure streaming write ----
    const int fid = blockIdx.x - 768;     // [0, 2688)
    const int bh  = fid / 28;
    const int t   = fid % 28;
    const int mi  = LOWER28[t] >> 4, ni = LOWER28[t] & 15;
    const int b   = bh / NHEADS;
    const int m0  = mi * 128, n0 = ni * 128;
    const int* mb = mask + b * SEQ;
    float* ob = out + (size_t)bh * SEQ * SEQ;
    const int c0 = (tid & 31) * 4;        // 32 threads x 4 cols = 128 cols
    const int r0 = tid >> 5;              // 8 rows per sweep
    f32x4 np4;
    #pragma unroll
    for (int j = 0; j < 4; ++j) np4[j] = mb[n0 + c0 + j] ? 0.0f : NEGV;
    for (int r = r0; r < 128; r += 8) {
      const int gm = m0 + r;
      const float mp = (mb[gm] ? 0.0f : NEGV) + NEGV;
      f32x4 v;
      #pragma unroll
      for (int j = 0; j < 4; ++j) v[j] = -(np4[j] + mp) * 0.125f;
      __builtin_nontemporal_store(v, (f32x4*)(ob + (size_t)gm * SEQ + n0 + c0));
    }
    return;
  }

  // ---- projection path (identical to round-5/6 proven kernel) ----
  const int lane = tid & 63;
  const int wid  = tid >> 6;
  const int wm = wid >> 1, wn = wid & 1;
  const int orig = blockIdx.x;           // 0..767; XCD id = orig & 7
  const int wgid = (orig & 7) * 96 + (orig >> 3);
  const int m0 = (wgid / 12) * 128;
  const int n0 = (wgid % 12) * 128;

  const int srow = tid >> 3;
  const int g8   = ((tid & 7) ^ (srow & 7)) * 8;
  const ushort* gAb = A  + (size_t)(m0 + srow) * DIN + g8;
  const ushort* gBb = Bt + (size_t)(n0 + srow) * DIN + g8;

  const int kb = lane >> 4;
  int aoff[4][2], boff[4][2];
  #pragma unroll
  for (int i = 0; i < 4; ++i) {
    const int ra = wm * 64 + i * 16 + (lane & 15);
    const int rb = wn * 64 + i * 16 + (lane & 15);
    #pragma unroll
    for (int ks = 0; ks < 2; ++ks) {
      aoff[i][ks] = ra * 64 + ((ks * 4 + kb) ^ (ra & 7)) * 8;
      boff[i][ks] = rb * 64 + ((ks * 4 + kb) ^ (rb & 7)) * 8;
    }
  }

  f32x4 acc[4][4] = {};
  for (int kt = 0; kt < DIN / 64; ++kt) {
    __syncthreads();
    const int ko = kt * 64;
    #pragma unroll
    for (int is = 0; is < 4; ++is) {
      async16(gAb + (size_t)(is * 32) * DIN + ko, As + is * 2048 + wid * 512);
      async16(gBb + (size_t)(is * 32) * DIN + ko, Bs + is * 2048 + wid * 512);
    }
    __syncthreads();
    #pragma unroll
    for (int ks = 0; ks < 2; ++ks) {
      bf16x8 af[4], bfr[4];
      #pragma unroll
      for (int i = 0; i < 4; ++i) {
        af[i]  = *(const bf16x8*)(As + aoff[i][ks]);
        bfr[i] = *(const bf16x8*)(Bs + boff[i][ks]);
      }
      #pragma unroll
      for (int mi = 0; mi < 4; ++mi)
        #pragma unroll
        for (int ni = 0; ni < 4; ++ni)
          acc[mi][ni] = __builtin_amdgcn_mfma_f32_16x16x32_bf16(af[mi], bfr[ni], acc[mi][ni], 0, 0, 0);
    }
  }

  const int b = m0 >> 10;
  const int baserow = m0 + wm * 64 + ((lane >> 4) << 2);
  #pragma unroll
  for (int ni = 0; ni < 4; ++ni) {
    const int n = n0 + wn * 64 + ni * 16 + (lane & 15);
    const float bv = bias[n];
    const int h  = n >> 7;
    const int c  = n & 127;
    const int d  = c & 63;
    const int pi = d >> 1;
    ushort* dst = ((c < 64) ? Qb : Kb) + (size_t)(b * NHEADS + h) * SEQ * 64 + d;
    #pragma unroll
    for (int mi = 0; mi < 4; ++mi) {
      #pragma unroll
      for (int j = 0; j < 4; ++j) {
        const int gm = baserow + mi * 16 + j;
        const int s  = gm & (SEQ - 1);
        float v = acc[mi][ni][j] + bv;
        float p = __shfl_xor(v, 1);
        float2 sc = ((const float2*)tab)[s * 32 + pi];
        float o = (d & 1) ? fmaf(v, sc.y, p * sc.x) : fmaf(v, sc.y, -p * sc.x);
        dst[(size_t)s * 64] = f2bf(o);
      }
    }
  }
}

// ---------------- logits: QK^T + mask on upper+diagonal tiles only ----------------
__global__ __launch_bounds__(256) void k_logits(
    const ushort* __restrict__ Qb, const ushort* __restrict__ Kb,
    const int* __restrict__ mask, float* __restrict__ out) {
  __shared__ __align__(16) ushort Qs[128 * 64];
  __shared__ __align__(16) ushort Ks[128 * 64];
  const int tid  = threadIdx.x;
  const int lane = tid & 63;
  const int wid  = tid >> 6;
  const int wm = wid >> 1, wn = wid & 1;
  // XCD-aware remap (bijective: 3456 % 8 == 0; 432 consecutive wgid per XCD -> 12 bh each)
  const int orig = blockIdx.x;
  const int wgid = (orig & 7) * 432 + (orig >> 3);
  const int bh = wgid / 36;              // 0..95
  const int t  = wgid % 36;
  const int mi_ = UPPER36[t] >> 4, ni_ = UPPER36[t] & 15;
  const int b  = bh / NHEADS;
  const int m0 = mi_ * 128;
  const int n0 = ni_ * 128;
  const ushort* Qt = Qb + (size_t)bh * SEQ * 64;
  const ushort* Kt = Kb + (size_t)bh * SEQ * 64;

  #pragma unroll
  for (int is = 0; is < 4; ++is) {
    const int off = is * 4096 + tid * 16;
    const int row = off >> 7;
    const int g8  = ((((off >> 4) & 7) ^ (row & 7))) * 8;
    async16(Qt + (size_t)(m0 + row) * 64 + g8, Qs + is * 2048 + wid * 512);
    async16(Kt + (size_t)(n0 + row) * 64 + g8, Ks + is * 2048 + wid * 512);
  }
  __syncthreads();

  f32x4 acc[4][4] = {};
  const int kb = lane >> 4;
  #pragma unroll
  for (int ks = 0; ks < 2; ++ks) {
    bf16x8 qf[4], kf[4];
    #pragma unroll
    for (int i = 0; i < 4; ++i) {
      const int rq = wm * 64 + i * 16 + (lane & 15);
      qf[i] = *(const bf16x8*)(Qs + rq * 64 + ((ks * 4 + kb) ^ (rq & 7)) * 8);
      const int rk = wn * 64 + i * 16 + (lane & 15);
      kf[i] = *(const bf16x8*)(Ks + rk * 64 + ((ks * 4 + kb) ^ (rk & 7)) * 8);
    }
    #pragma unroll
    for (int mi = 0; mi < 4; ++mi)
      #pragma unroll
      for (int ni = 0; ni < 4; ++ni)
        acc[mi][ni] = __builtin_amdgcn_mfma_f32_16x16x32_bf16(qf[mi], kf[ni], acc[mi][ni], 0, 0, 0);
  }

  const int* mb = mask + b * SEQ;
  float* ob = out + (size_t)bh * SEQ * SEQ;
  const int mrow0 = m0 + wm * 64 + ((lane >> 4) << 2);
  const int ncol0 = n0 + wn * 64 + (lane & 15);
  float npen[4];
  int gn_[4];
  #pragma unroll
  for (int ni = 0; ni < 4; ++ni) {
    gn_[ni]  = ncol0 + ni * 16;
    npen[ni] = mb[gn_[ni]] ? 0.0f : NEGV;
  }
  #pragma unroll
  for (int mi = 0; mi < 4; ++mi) {
    #pragma unroll
    for (int j = 0; j < 4; ++j) {
      const int gm = mrow0 + mi * 16 + j;
      const float mpen = mb[gm] ? 0.0f : NEGV;
      float* orow = ob + (size_t)gm * SEQ;
      #pragma unroll
      for (int ni = 0; ni < 4; ++ni) {
        const int gn = gn_[ni];
        const float tpen = (gm > gn) ? NEGV : 0.0f;
        const float v = (acc[mi][ni][j] - (mpen + npen[ni] + tpen)) * 0.125f;
        __builtin_nontemporal_store(v, &orow[gn]);  // write-once stream: keep Q/K resident
      }
    }
  }
}

// ---------------- launcher ----------------
extern "C" void kernel_launch(void* const* d_in, const int* in_sizes, int n_in,
                              void* d_out, int out_size, void* d_ws, size_t ws_size,
                              hipStream_t stream) {
  const float* inp  = (const float*)d_in[0];  // [8][1024][1024]
  const float* W    = (const float*)d_in[1];  // [1024][1536]
  const float* bias = (const float*)d_in[2];  // [1536]
  const int*   mask = (const int*)d_in[3];    // [8][1024]
  float* out = (float*)d_out;                 // [8][12][1024][1024]

  char* ws = (char*)d_ws;
  ushort* A16  = (ushort*)ws;                 // 16,777,216 B
  ushort* WT16 = (ushort*)(ws + 16777216);    //  3,145,728 B
  float*  tab  = (float*)(ws + 19922944);     //    262,144 B
  ushort* Qb   = (ushort*)(ws + 20185088);    // 12,582,912 B
  ushort* Kb   = (ushort*)(ws + 32768000);    // 12,582,912 B  (total ~45.4 MB)

  k_prep<<<2560, 256, 0, stream>>>(inp, W, A16, WT16, tab);
  k_proj_fill<<<3456, 256, 0, stream>>>(A16, WT16, bias, tab, Qb, Kb, mask, out);
  k_logits<<<3456, 256, 0, stream>>>(Qb, Kb, mask, out);
}

// Round 10
// 126.129 us; speedup vs baseline: 1.2087x; 1.2087x over previous
//
#include <hip/hip_runtime.h>
#include <hip/hip_bf16.h>
#include <stdint.h>

#define NHEADS 12
#define HSZ 64
#define BATCH 8
#define SEQ 1024
#define DIN 1024
#define NPROJ 1536   // NHEADS*HSZ*2
#define MTOK 8192    // BATCH*SEQ
#define NEGV 1e12f

typedef float  f32x4  __attribute__((ext_vector_type(4)));
typedef __bf16 bf16x8 __attribute__((ext_vector_type(8)));

__device__ __forceinline__ ushort f2bf(float x) {
  union { float f; uint32_t u; } v; v.f = x;
  uint32_t r = v.u + 0x7FFFu + ((v.u >> 16) & 1u);
  return (ushort)(r >> 16);
}

__device__ __forceinline__ void async16(const void* g, void* l) {
  __builtin_amdgcn_global_load_lds(
      (const __attribute__((address_space(1))) uint32_t*)g,
      (__attribute__((address_space(3))) uint32_t*)l,
      16, 0, 0);
}

// ---------------- merged prep kernel ----------------
__global__ __launch_bounds__(256) void k_prep(
    const float* __restrict__ inp, const float* __restrict__ W,
    ushort* __restrict__ A16, ushort* __restrict__ Wt, float* __restrict__ tab) {
  const int blk = blockIdx.x;
  const int tid = threadIdx.x;
  if (blk < 2048) {
    const float4* in4 = (const float4*)inp;
    ushort4* out4 = (ushort4*)A16;
    const int n4 = MTOK * DIN / 4;
    int i = blk * 256 + tid;
    for (; i < n4; i += 2048 * 256) {
      float4 v = in4[i];
      ushort4 o;
      o.x = f2bf(v.x); o.y = f2bf(v.y); o.z = f2bf(v.z); o.w = f2bf(v.w);
      out4[i] = o;
    }
  } else if (blk < 2432) {
    __shared__ float tile[64][65];
    const int bb = blk - 2048;           // 384 = 24 x 16
    const int n0 = (bb % 24) * 64;
    const int k0 = (bb / 24) * 64;
    const int c  = tid & 63;
    const int r0 = (tid >> 6) * 16;
    #pragma unroll
    for (int rr = 0; rr < 16; ++rr)
      tile[r0 + rr][c] = W[(size_t)(k0 + r0 + rr) * NPROJ + n0 + c];
    __syncthreads();
    #pragma unroll
    for (int rr = 0; rr < 16; ++rr)
      Wt[(size_t)(n0 + r0 + rr) * DIN + k0 + c] = f2bf(tile[c][r0 + rr]);
  } else {
    const int t = (blk - 2432) * 256 + tid;  // 32768 total
    const int s = t >> 5, i = t & 31;
    const float p   = powf(10000.0f, (float)i / 32.0f);
    const float ang = (float)s / p;
    tab[2 * t]     = sinf(ang);
    tab[2 * t + 1] = cosf(ang);
  }
}

// ---------------- projection GEMM + RoPE (pure, 768 blocks; r5-proven) ----------------
__global__ __launch_bounds__(256) void k_gemm_proj(
    const ushort* __restrict__ A, const ushort* __restrict__ Bt,
    const float* __restrict__ bias, const float* __restrict__ tab,
    ushort* __restrict__ Qb, ushort* __restrict__ Kb) {
  __shared__ __align__(16) ushort As[128 * 64];
  __shared__ __align__(16) ushort Bs[128 * 64];
  const int tid  = threadIdx.x;
  const int lane = tid & 63;
  const int wid  = tid >> 6;
  const int wm = wid >> 1, wn = wid & 1;
  // XCD-aware remap (bijective: 768 % 8 == 0)
  const int orig = blockIdx.x;
  const int wgid = (orig & 7) * 96 + (orig >> 3);
  const int m0 = (wgid / 12) * 128;
  const int n0 = (wgid % 12) * 128;

  const int srow = tid >> 3;
  const int g8   = ((tid & 7) ^ (srow & 7)) * 8;
  const ushort* gAb = A  + (size_t)(m0 + srow) * DIN + g8;
  const ushort* gBb = Bt + (size_t)(n0 + srow) * DIN + g8;

  const int kb = lane >> 4;
  int aoff[4][2], boff[4][2];
  #pragma unroll
  for (int i = 0; i < 4; ++i) {
    const int ra = wm * 64 + i * 16 + (lane & 15);
    const int rb = wn * 64 + i * 16 + (lane & 15);
    #pragma unroll
    for (int ks = 0; ks < 2; ++ks) {
      aoff[i][ks] = ra * 64 + ((ks * 4 + kb) ^ (ra & 7)) * 8;
      boff[i][ks] = rb * 64 + ((ks * 4 + kb) ^ (rb & 7)) * 8;
    }
  }

  f32x4 acc[4][4] = {};
  for (int kt = 0; kt < DIN / 64; ++kt) {
    __syncthreads();
    const int ko = kt * 64;
    #pragma unroll
    for (int is = 0; is < 4; ++is) {
      async16(gAb + (size_t)(is * 32) * DIN + ko, As + is * 2048 + wid * 512);
      async16(gBb + (size_t)(is * 32) * DIN + ko, Bs + is * 2048 + wid * 512);
    }
    __syncthreads();
    #pragma unroll
    for (int ks = 0; ks < 2; ++ks) {
      bf16x8 af[4], bfr[4];
      #pragma unroll
      for (int i = 0; i < 4; ++i) {
        af[i]  = *(const bf16x8*)(As + aoff[i][ks]);
        bfr[i] = *(const bf16x8*)(Bs + boff[i][ks]);
      }
      #pragma unroll
      for (int mi = 0; mi < 4; ++mi)
        #pragma unroll
        for (int ni = 0; ni < 4; ++ni)
          acc[mi][ni] = __builtin_amdgcn_mfma_f32_16x16x32_bf16(af[mi], bfr[ni], acc[mi][ni], 0, 0, 0);
    }
  }

  const int b = m0 >> 10;
  const int baserow = m0 + wm * 64 + ((lane >> 4) << 2);
  #pragma unroll
  for (int ni = 0; ni < 4; ++ni) {
    const int n = n0 + wn * 64 + ni * 16 + (lane & 15);
    const float bv = bias[n];
    const int h  = n >> 7;
    const int c  = n & 127;
    const int d  = c & 63;
    const int pi = d >> 1;
    ushort* dst = ((c < 64) ? Qb : Kb) + (size_t)(b * NHEADS + h) * SEQ * 64 + d;
    #pragma unroll
    for (int mi = 0; mi < 4; ++mi) {
      #pragma unroll
      for (int j = 0; j < 4; ++j) {
        const int gm = baserow + mi * 16 + j;
        const int s  = gm & (SEQ - 1);
        float v = acc[mi][ni][j] + bv;
        float p = __shfl_xor(v, 1);
        float2 sc = ((const float2*)tab)[s * 32 + pi];
        float o = (d & 1) ? fmaf(v, sc.y, p * sc.x) : fmaf(v, sc.y, -p * sc.x);
        dst[(size_t)s * 64] = f2bf(o);
      }
    }
  }
}

// ---------------- output: all 64 tiles per bh ----------------
// upper/diag (mi<=ni): QK^T MFMA + mask, plain stores (r9: nt scalar stores are 2x slower)
// lower (mi>ni): fully causal-masked -> pure f32x4 nt streaming fill (no LDS/stage).
// Both are write-dominated, so co-residency shares the write path (unlike proj,
// whose vmcnt-drain K-loop is poisoned by a co-resident write stream; r7/r8).
__global__ __launch_bounds__(256) void k_out(
    const ushort* __restrict__ Qb, const ushort* __restrict__ Kb,
    const int* __restrict__ mask, float* __restrict__ out) {
  __shared__ __align__(16) ushort Qs[128 * 64];
  __shared__ __align__(16) ushort Ks[128 * 64];
  const int tid  = threadIdx.x;
  // XCD-aware remap (bijective: 6144 % 8 == 0; 768 wgid per XCD = 12 bh)
  const int orig = blockIdx.x;
  const int wgid = (orig & 7) * 768 + (orig >> 3);
  const int bh = wgid >> 6;              // 0..95
  const int b  = bh / NHEADS;
  const int mi_ = (wgid >> 3) & 7;
  const int ni_ = wgid & 7;
  const int m0 = mi_ * 128;
  const int n0 = ni_ * 128;
  const int* mb = mask + b * SEQ;
  float* ob = out + (size_t)bh * SEQ * SEQ;

  if (mi_ > ni_) {
    // ---- causal fill path ----
    const int c0 = (tid & 31) * 4;        // 32 threads x 4 cols = 128 cols
    const int r0 = tid >> 5;              // 8 rows per sweep
    f32x4 np4;
    #pragma unroll
    for (int j = 0; j < 4; ++j) np4[j] = mb[n0 + c0 + j] ? 0.0f : NEGV;
    for (int r = r0; r < 128; r += 8) {
      const int gm = m0 + r;
      const float mp = (mb[gm] ? 0.0f : NEGV) + NEGV;
      f32x4 v;
      #pragma unroll
      for (int j = 0; j < 4; ++j) v[j] = -(np4[j] + mp) * 0.125f;
      __builtin_nontemporal_store(v, (f32x4*)(ob + (size_t)gm * SEQ + n0 + c0));
    }
    return;
  }

  // ---- MFMA path (r6-proven) ----
  const int lane = tid & 63;
  const int wid  = tid >> 6;
  const int wm = wid >> 1, wn = wid & 1;
  const ushort* Qt = Qb + (size_t)bh * SEQ * 64;
  const ushort* Kt = Kb + (size_t)bh * SEQ * 64;

  #pragma unroll
  for (int is = 0; is < 4; ++is) {
    const int off = is * 4096 + tid * 16;
    const int row = off >> 7;
    const int g8  = ((((off >> 4) & 7) ^ (row & 7))) * 8;
    async16(Qt + (size_t)(m0 + row) * 64 + g8, Qs + is * 2048 + wid * 512);
    async16(Kt + (size_t)(n0 + row) * 64 + g8, Ks + is * 2048 + wid * 512);
  }
  __syncthreads();

  f32x4 acc[4][4] = {};
  const int kb = lane >> 4;
  #pragma unroll
  for (int ks = 0; ks < 2; ++ks) {
    bf16x8 qf[4], kf[4];
    #pragma unroll
    for (int i = 0; i < 4; ++i) {
      const int rq = wm * 64 + i * 16 + (lane & 15);
      qf[i] = *(const bf16x8*)(Qs + rq * 64 + ((ks * 4 + kb) ^ (rq & 7)) * 8);
      const int rk = wn * 64 + i * 16 + (lane & 15);
      kf[i] = *(const bf16x8*)(Ks + rk * 64 + ((ks * 4 + kb) ^ (rk & 7)) * 8);
    }
    #pragma unroll
    for (int mi = 0; mi < 4; ++mi)
      #pragma unroll
      for (int ni = 0; ni < 4; ++ni)
        acc[mi][ni] = __builtin_amdgcn_mfma_f32_16x16x32_bf16(qf[mi], kf[ni], acc[mi][ni], 0, 0, 0);
  }

  const int mrow0 = m0 + wm * 64 + ((lane >> 4) << 2);
  const int ncol0 = n0 + wn * 64 + (lane & 15);
  float npen[4];
  int gn_[4];
  #pragma unroll
  for (int ni = 0; ni < 4; ++ni) {
    gn_[ni]  = ncol0 + ni * 16;
    npen[ni] = mb[gn_[ni]] ? 0.0f : NEGV;
  }
  #pragma unroll
  for (int mi = 0; mi < 4; ++mi) {
    #pragma unroll
    for (int j = 0; j < 4; ++j) {
      const int gm = mrow0 + mi * 16 + j;
      const float mpen = mb[gm] ? 0.0f : NEGV;
      float* orow = ob + (size_t)gm * SEQ;
      #pragma unroll
      for (int ni = 0; ni < 4; ++ni) {
        const int gn = gn_[ni];
        const float tpen = (gm > gn) ? NEGV : 0.0f;
        orow[gn] = (acc[mi][ni][j] - (mpen + npen[ni] + tpen)) * 0.125f;
      }
    }
  }
}

// ---------------- launcher ----------------
extern "C" void kernel_launch(void* const* d_in, const int* in_sizes, int n_in,
                              void* d_out, int out_size, void* d_ws, size_t ws_size,
                              hipStream_t stream) {
  const float* inp  = (const float*)d_in[0];  // [8][1024][1024]
  const float* W    = (const float*)d_in[1];  // [1024][1536]
  const float* bias = (const float*)d_in[2];  // [1536]
  const int*   mask = (const int*)d_in[3];    // [8][1024]
  float* out = (float*)d_out;                 // [8][12][1024][1024]

  char* ws = (char*)d_ws;
  ushort* A16  = (ushort*)ws;                 // 16,777,216 B
  ushort* WT16 = (ushort*)(ws + 16777216);    //  3,145,728 B
  float*  tab  = (float*)(ws + 19922944);     //    262,144 B
  ushort* Qb   = (ushort*)(ws + 20185088);    // 12,582,912 B
  ushort* Kb   = (ushort*)(ws + 32768000);    // 12,582,912 B  (total ~45.4 MB)

  k_prep<<<2560, 256, 0, stream>>>(inp, W, A16, WT16, tab);
  k_gemm_proj<<<768, 256, 0, stream>>>(A16, WT16, bias, tab, Qb, Kb);
  k_out<<<6144, 256, 0, stream>>>(Qb, Kb, mask, out);
}

// Round 11
// 119.186 us; speedup vs baseline: 1.2792x; 1.0583x over previous
//
#include <hip/hip_runtime.h>
#include <hip/hip_bf16.h>
#include <stdint.h>

#define NHEADS 12
#define HSZ 64
#define BATCH 8
#define SEQ 1024
#define DIN 1024
#define NPROJ 1536   // NHEADS*HSZ*2
#define MTOK 8192    // BATCH*SEQ
#define NEGV 1e12f

typedef float  f32x4  __attribute__((ext_vector_type(4)));
typedef __bf16 bf16x8 __attribute__((ext_vector_type(8)));

__device__ __forceinline__ ushort f2bf(float x) {
  union { float f; uint32_t u; } v; v.f = x;
  uint32_t r = v.u + 0x7FFFu + ((v.u >> 16) & 1u);
  return (ushort)(r >> 16);
}

__device__ __forceinline__ void async16(const void* g, void* l) {
  __builtin_amdgcn_global_load_lds(
      (const __attribute__((address_space(1))) uint32_t*)g,
      (__attribute__((address_space(3))) uint32_t*)l,
      16, 0, 0);
}

// ---------------- merged prep kernel ----------------
__global__ __launch_bounds__(256) void k_prep(
    const float* __restrict__ inp, const float* __restrict__ W,
    ushort* __restrict__ A16, ushort* __restrict__ Wt, float* __restrict__ tab) {
  const int blk = blockIdx.x;
  const int tid = threadIdx.x;
  if (blk < 2048) {
    const float4* in4 = (const float4*)inp;
    ushort4* out4 = (ushort4*)A16;
    const int n4 = MTOK * DIN / 4;
    int i = blk * 256 + tid;
    for (; i < n4; i += 2048 * 256) {
      float4 v = in4[i];
      ushort4 o;
      o.x = f2bf(v.x); o.y = f2bf(v.y); o.z = f2bf(v.z); o.w = f2bf(v.w);
      out4[i] = o;
    }
  } else if (blk < 2432) {
    __shared__ float tile[64][65];
    const int bb = blk - 2048;           // 384 = 24 x 16
    const int n0 = (bb % 24) * 64;
    const int k0 = (bb / 24) * 64;
    const int c  = tid & 63;
    const int r0 = (tid >> 6) * 16;
    #pragma unroll
    for (int rr = 0; rr < 16; ++rr)
      tile[r0 + rr][c] = W[(size_t)(k0 + r0 + rr) * NPROJ + n0 + c];
    __syncthreads();
    #pragma unroll
    for (int rr = 0; rr < 16; ++rr)
      Wt[(size_t)(n0 + r0 + rr) * DIN + k0 + c] = f2bf(tile[c][r0 + rr]);
  } else {
    const int t = (blk - 2432) * 256 + tid;  // 32768 total
    const int s = t >> 5, i = t & 31;
    const float p   = powf(10000.0f, (float)i / 32.0f);
    const float ang = (float)s / p;
    tab[2 * t]     = sinf(ang);
    tab[2 * t + 1] = cosf(ang);
  }
}

// ---------------- projection GEMM + RoPE (BK=32 double-buffered pipeline) ----------------
// T3-minimum recipe: issue STAGE(t+1) into buf^1 BEFORE compute(t); one
// __syncthreads per K-step (drains vmcnt for buf^1 stage + lgkm reads of buf).
// 32 KB LDS total -> occupancy preserved (r4 evidence, re-attributed in r10 PM).
__global__ __launch_bounds__(256, 3) void k_gemm_proj(
    const ushort* __restrict__ A, const ushort* __restrict__ Bt,
    const float* __restrict__ bias, const float* __restrict__ tab,
    ushort* __restrict__ Qb, ushort* __restrict__ Kb) {
  __shared__ __align__(16) ushort As[2][128 * 32];
  __shared__ __align__(16) ushort Bs[2][128 * 32];
  const int tid  = threadIdx.x;
  const int lane = tid & 63;
  const int wid  = tid >> 6;
  const int wm = wid >> 1, wn = wid & 1;
  // XCD-aware remap (bijective: 768 % 8 == 0)
  const int orig = blockIdx.x;
  const int wgid = (orig & 7) * 96 + (orig >> 3);
  const int m0 = (wgid / 12) * 128;
  const int n0 = (wgid % 12) * 128;

  // staging: linear LDS layout [row][32] bf16 (64 B rows, 4 x 16B slots).
  // swizzle: slot_lds = slot_global ^ ((row>>1)&3)  (involution; applied to SOURCE)
  const int off0 = tid * 16;         // issue-0 linear byte offset in tile
  const int off1 = 4096 + tid * 16;  // issue-1
  const int r0 = off0 >> 6, s0 = (off0 >> 4) & 3;
  const int r1 = off1 >> 6, s1 = (off1 >> 4) & 3;
  const int g0 = (s0 ^ ((r0 >> 1) & 3)) * 8;  // global k-chunk (elements)
  const int g1 = (s1 ^ ((r1 >> 1) & 3)) * 8;
  const ushort* gA0 = A  + (size_t)(m0 + r0) * DIN + g0;
  const ushort* gA1 = A  + (size_t)(m0 + r1) * DIN + g1;
  const ushort* gB0 = Bt + (size_t)(n0 + r0) * DIN + g0;
  const ushort* gB1 = Bt + (size_t)(n0 + r1) * DIN + g1;

  // fragment read offsets (ushort units), same swizzle on READ side
  const int kb = lane >> 4;
  int aoff[4], boff[4];
  #pragma unroll
  for (int i = 0; i < 4; ++i) {
    const int ra = wm * 64 + i * 16 + (lane & 15);
    aoff[i] = ra * 32 + (kb ^ ((ra >> 1) & 3)) * 8;
    const int rb = wn * 64 + i * 16 + (lane & 15);
    boff[i] = rb * 32 + (kb ^ ((rb >> 1) & 3)) * 8;
  }

  f32x4 acc[4][4] = {};
  // prologue: stage tile 0 into buffer 0
  async16(gA0, As[0] + wid * 512);
  async16(gA1, As[0] + 2048 + wid * 512);
  async16(gB0, Bs[0] + wid * 512);
  async16(gB1, Bs[0] + 2048 + wid * 512);
  __syncthreads();

  int cur = 0;
  #pragma unroll 2
  for (int kt = 0; kt < DIN / 32; ++kt) {
    if (kt + 1 < DIN / 32) {       // issue next tile's loads first (overlap)
      const int ko = (kt + 1) * 32;
      ushort* ad = As[cur ^ 1];
      ushort* bd = Bs[cur ^ 1];
      async16(gA0 + ko, ad + wid * 512);
      async16(gA1 + ko, ad + 2048 + wid * 512);
      async16(gB0 + ko, bd + wid * 512);
      async16(gB1 + ko, bd + 2048 + wid * 512);
    }
    const ushort* ab = As[cur];
    const ushort* bb = Bs[cur];
    bf16x8 af[4], bfr[4];
    #pragma unroll
    for (int i = 0; i < 4; ++i) {
      af[i]  = *(const bf16x8*)(ab + aoff[i]);
      bfr[i] = *(const bf16x8*)(bb + boff[i]);
    }
    #pragma unroll
    for (int mi = 0; mi < 4; ++mi)
      #pragma unroll
      for (int ni = 0; ni < 4; ++ni)
        acc[mi][ni] = __builtin_amdgcn_mfma_f32_16x16x32_bf16(af[mi], bfr[ni], acc[mi][ni], 0, 0, 0);
    __syncthreads();   // drains lgkm (reads of cur) + vmcnt (stage of cur^1)
    cur ^= 1;
  }

  // epilogue: bias + RoPE + scatter to Q/K (bf16)
  const int b = m0 >> 10;  // 128-tile never crosses a batch boundary
  const int baserow = m0 + wm * 64 + ((lane >> 4) << 2);
  #pragma unroll
  for (int ni = 0; ni < 4; ++ni) {
    const int n = n0 + wn * 64 + ni * 16 + (lane & 15);
    const float bv = bias[n];
    const int h  = n >> 7;
    const int c  = n & 127;
    const int d  = c & 63;
    const int pi = d >> 1;
    ushort* dst = ((c < 64) ? Qb : Kb) + (size_t)(b * NHEADS + h) * SEQ * 64 + d;
    #pragma unroll
    for (int mi = 0; mi < 4; ++mi) {
      #pragma unroll
      for (int j = 0; j < 4; ++j) {
        const int gm = baserow + mi * 16 + j;
        const int s  = gm & (SEQ - 1);
        float v = acc[mi][ni][j] + bv;
        float p = __shfl_xor(v, 1);  // paired channel (n^1) lives in lane^1
        float2 sc = ((const float2*)tab)[s * 32 + pi];
        float o = (d & 1) ? fmaf(v, sc.y, p * sc.x) : fmaf(v, sc.y, -p * sc.x);
        dst[(size_t)s * 64] = f2bf(o);
      }
    }
  }
}

// ---------------- output: all 64 tiles per bh (r10-proven) ----------------
__global__ __launch_bounds__(256) void k_out(
    const ushort* __restrict__ Qb, const ushort* __restrict__ Kb,
    const int* __restrict__ mask, float* __restrict__ out) {
  __shared__ __align__(16) ushort Qs[128 * 64];
  __shared__ __align__(16) ushort Ks[128 * 64];
  const int tid  = threadIdx.x;
  // XCD-aware remap (bijective: 6144 % 8 == 0; 768 wgid per XCD = 12 bh)
  const int orig = blockIdx.x;
  const int wgid = (orig & 7) * 768 + (orig >> 3);
  const int bh = wgid >> 6;              // 0..95
  const int b  = bh / NHEADS;
  const int mi_ = (wgid >> 3) & 7;
  const int ni_ = wgid & 7;
  const int m0 = mi_ * 128;
  const int n0 = ni_ * 128;
  const int* mb = mask + b * SEQ;
  float* ob = out + (size_t)bh * SEQ * SEQ;

  if (mi_ > ni_) {
    // ---- causal fill path: coalesced f32x4 nt streaming write ----
    const int c0 = (tid & 31) * 4;
    const int r0 = tid >> 5;
    f32x4 np4;
    #pragma unroll
    for (int j = 0; j < 4; ++j) np4[j] = mb[n0 + c0 + j] ? 0.0f : NEGV;
    for (int r = r0; r < 128; r += 8) {
      const int gm = m0 + r;
      const float mp = (mb[gm] ? 0.0f : NEGV) + NEGV;
      f32x4 v;
      #pragma unroll
      for (int j = 0; j < 4; ++j) v[j] = -(np4[j] + mp) * 0.125f;
      __builtin_nontemporal_store(v, (f32x4*)(ob + (size_t)gm * SEQ + n0 + c0));
    }
    return;
  }

  // ---- MFMA path (plain stores; r9: scalar nt stores are 2x slower) ----
  const int lane = tid & 63;
  const int wid  = tid >> 6;
  const int wm = wid >> 1, wn = wid & 1;
  const ushort* Qt = Qb + (size_t)bh * SEQ * 64;
  const ushort* Kt = Kb + (size_t)bh * SEQ * 64;

  #pragma unroll
  for (int is = 0; is < 4; ++is) {
    const int off = is * 4096 + tid * 16;
    const int row = off >> 7;
    const int g8  = ((((off >> 4) & 7) ^ (row & 7))) * 8;
    async16(Qt + (size_t)(m0 + row) * 64 + g8, Qs + is * 2048 + wid * 512);
    async16(Kt + (size_t)(n0 + row) * 64 + g8, Ks + is * 2048 + wid * 512);
  }
  __syncthreads();

  f32x4 acc[4][4] = {};
  const int kb = lane >> 4;
  #pragma unroll
  for (int ks = 0; ks < 2; ++ks) {
    bf16x8 qf[4], kf[4];
    #pragma unroll
    for (int i = 0; i < 4; ++i) {
      const int rq = wm * 64 + i * 16 + (lane & 15);
      qf[i] = *(const bf16x8*)(Qs + rq * 64 + ((ks * 4 + kb) ^ (rq & 7)) * 8);
      const int rk = wn * 64 + i * 16 + (lane & 15);
      kf[i] = *(const bf16x8*)(Ks + rk * 64 + ((ks * 4 + kb) ^ (rk & 7)) * 8);
    }
    #pragma unroll
    for (int mi = 0; mi < 4; ++mi)
      #pragma unroll
      for (int ni = 0; ni < 4; ++ni)
        acc[mi][ni] = __builtin_amdgcn_mfma_f32_16x16x32_bf16(qf[mi], kf[ni], acc[mi][ni], 0, 0, 0);
  }

  const int mrow0 = m0 + wm * 64 + ((lane >> 4) << 2);
  const int ncol0 = n0 + wn * 64 + (lane & 15);
  float npen[4];
  int gn_[4];
  #pragma unroll
  for (int ni = 0; ni < 4; ++ni) {
    gn_[ni]  = ncol0 + ni * 16;
    npen[ni] = mb[gn_[ni]] ? 0.0f : NEGV;
  }
  #pragma unroll
  for (int mi = 0; mi < 4; ++mi) {
    #pragma unroll
    for (int j = 0; j < 4; ++j) {
      const int gm = mrow0 + mi * 16 + j;
      const float mpen = mb[gm] ? 0.0f : NEGV;
      float* orow = ob + (size_t)gm * SEQ;
      #pragma unroll
      for (int ni = 0; ni < 4; ++ni) {
        const int gn = gn_[ni];
        const float tpen = (gm > gn) ? NEGV : 0.0f;
        orow[gn] = (acc[mi][ni][j] - (mpen + npen[ni] + tpen)) * 0.125f;
      }
    }
  }
}

// ---------------- launcher ----------------
extern "C" void kernel_launch(void* const* d_in, const int* in_sizes, int n_in,
                              void* d_out, int out_size, void* d_ws, size_t ws_size,
                              hipStream_t stream) {
  const float* inp  = (const float*)d_in[0];  // [8][1024][1024]
  const float* W    = (const float*)d_in[1];  // [1024][1536]
  const float* bias = (const float*)d_in[2];  // [1536]
  const int*   mask = (const int*)d_in[3];    // [8][1024]
  float* out = (float*)d_out;                 // [8][12][1024][1024]

  char* ws = (char*)d_ws;
  ushort* A16  = (ushort*)ws;                 // 16,777,216 B
  ushort* WT16 = (ushort*)(ws + 16777216);    //  3,145,728 B
  float*  tab  = (float*)(ws + 19922944);     //    262,144 B
  ushort* Qb   = (ushort*)(ws + 20185088);    // 12,582,912 B
  ushort* Kb   = (ushort*)(ws + 32768000);    // 12,582,912 B  (total ~45.4 MB)

  k_prep<<<2560, 256, 0, stream>>>(inp, W, A16, WT16, tab);
  k_gemm_proj<<<768, 256, 0, stream>>>(A16, WT16, bias, tab, Qb, Kb);
  k_out<<<6144, 256, 0, stream>>>(Qb, Kb, mask, out);
}

// Round 12
// 118.181 us; speedup vs baseline: 1.2900x; 1.0085x over previous
//
#include <hip/hip_runtime.h>
#include <hip/hip_bf16.h>
#include <stdint.h>

#define NHEADS 12
#define HSZ 64
#define BATCH 8
#define SEQ 1024
#define DIN 1024
#define NPROJ 1536   // NHEADS*HSZ*2
#define MTOK 8192    // BATCH*SEQ
#define NEGV 1e12f

typedef float  f32x4  __attribute__((ext_vector_type(4)));
typedef __bf16 bf16x8 __attribute__((ext_vector_type(8)));

__device__ __forceinline__ ushort f2bf(float x) {
  union { float f; uint32_t u; } v; v.f = x;
  uint32_t r = v.u + 0x7FFFu + ((v.u >> 16) & 1u);
  return (ushort)(r >> 16);
}

__device__ __forceinline__ void async16(const void* g, void* l) {
  __builtin_amdgcn_global_load_lds(
      (const __attribute__((address_space(1))) uint32_t*)g,
      (__attribute__((address_space(3))) uint32_t*)l,
      16, 0, 0);
}

// ---------------- merged prep kernel ----------------
__global__ __launch_bounds__(256) void k_prep(
    const float* __restrict__ inp, const float* __restrict__ W,
    ushort* __restrict__ A16, ushort* __restrict__ Wt, float* __restrict__ tab) {
  const int blk = blockIdx.x;
  const int tid = threadIdx.x;
  if (blk < 2048) {
    const float4* in4 = (const float4*)inp;
    ushort4* out4 = (ushort4*)A16;
    const int n4 = MTOK * DIN / 4;
    int i = blk * 256 + tid;
    for (; i < n4; i += 2048 * 256) {
      float4 v = in4[i];
      ushort4 o;
      o.x = f2bf(v.x); o.y = f2bf(v.y); o.z = f2bf(v.z); o.w = f2bf(v.w);
      out4[i] = o;
    }
  } else if (blk < 2432) {
    __shared__ float tile[64][65];
    const int bb = blk - 2048;           // 384 = 24 x 16
    const int n0 = (bb % 24) * 64;
    const int k0 = (bb / 24) * 64;
    const int c  = tid & 63;
    const int r0 = (tid >> 6) * 16;
    #pragma unroll
    for (int rr = 0; rr < 16; ++rr)
      tile[r0 + rr][c] = W[(size_t)(k0 + r0 + rr) * NPROJ + n0 + c];
    __syncthreads();
    #pragma unroll
    for (int rr = 0; rr < 16; ++rr)
      Wt[(size_t)(n0 + r0 + rr) * DIN + k0 + c] = f2bf(tile[c][r0 + rr]);
  } else {
    const int t = (blk - 2432) * 256 + tid;  // 32768 total
    const int s = t >> 5, i = t & 31;
    const float p   = powf(10000.0f, (float)i / 32.0f);
    const float ang = (float)s / p;
    tab[2 * t]     = sinf(ang);
    tab[2 * t + 1] = cosf(ang);
  }
}

// ------- projection GEMM + RoPE: BK=32, 3-deep prefetch, counted vmcnt -------
// Pipeline (T4): per iter t -> s_waitcnt vmcnt(4) [stage(t) complete, stage(t+1)
// may fly] -> raw s_barrier (no vmcnt(0) drain) -> issue stage(t+2) -> ds_read
// buf(t) -> MFMA. Each stage gets ~2 compute windows to land.
// Hazards: stage(t+2) writes buf[(t+2)%3]=buf[(t-1)%3], whose reads (iter t-1)
// finished before each wave's MFMA(t-1) (lgkmcnt) which precedes barrier(t).
__global__ __launch_bounds__(256, 3) void k_gemm_proj(
    const ushort* __restrict__ A, const ushort* __restrict__ Bt,
    const float* __restrict__ bias, const float* __restrict__ tab,
    ushort* __restrict__ Qb, ushort* __restrict__ Kb) {
  __shared__ __align__(16) ushort As[3][128 * 32];
  __shared__ __align__(16) ushort Bs[3][128 * 32];
  const int tid  = threadIdx.x;
  const int lane = tid & 63;
  const int wid  = tid >> 6;
  const int wm = wid >> 1, wn = wid & 1;
  // XCD-aware remap (bijective: 768 % 8 == 0)
  const int orig = blockIdx.x;
  const int wgid = (orig & 7) * 96 + (orig >> 3);
  const int m0 = (wgid / 12) * 128;
  const int n0 = (wgid % 12) * 128;

  // staging: linear LDS layout [row][32] bf16 (64 B rows, 4 x 16B slots).
  // swizzle: slot_lds = slot_global ^ ((row>>1)&3)  (involution; applied to SOURCE)
  const int off0 = tid * 16;         // issue-0 linear byte offset in tile
  const int off1 = 4096 + tid * 16;  // issue-1
  const int r0 = off0 >> 6, s0 = (off0 >> 4) & 3;
  const int r1 = off1 >> 6, s1 = (off1 >> 4) & 3;
  const int g0 = (s0 ^ ((r0 >> 1) & 3)) * 8;  // global k-chunk (elements)
  const int g1 = (s1 ^ ((r1 >> 1) & 3)) * 8;
  const ushort* gA0 = A  + (size_t)(m0 + r0) * DIN + g0;
  const ushort* gA1 = A  + (size_t)(m0 + r1) * DIN + g1;
  const ushort* gB0 = Bt + (size_t)(n0 + r0) * DIN + g0;
  const ushort* gB1 = Bt + (size_t)(n0 + r1) * DIN + g1;

  // fragment read offsets (ushort units), same swizzle on READ side
  const int kb = lane >> 4;
  int aoff[4], boff[4];
  #pragma unroll
  for (int i = 0; i < 4; ++i) {
    const int ra = wm * 64 + i * 16 + (lane & 15);
    aoff[i] = ra * 32 + (kb ^ ((ra >> 1) & 3)) * 8;
    const int rb = wn * 64 + i * 16 + (lane & 15);
    boff[i] = rb * 32 + (kb ^ ((rb >> 1) & 3)) * 8;
  }

  const int lA = wid * 512;     // per-wave LDS staging offsets (ushort units)
  const int lB = 2048 + wid * 512;

  // rotating buffer pointers: a0/b0 = current (tile t), a2/b2 = stage target (t+2)
  ushort *a0 = As[0], *a1 = As[1], *a2 = As[2];
  ushort *b0 = Bs[0], *b1 = Bs[1], *b2 = Bs[2];

  f32x4 acc[4][4] = {};
  // prologue: stage tiles 0,1 into buffers 0,1  (4 vmcnt events each)
  async16(gA0,      a0 + lA); async16(gA1,      a0 + lB);
  async16(gB0,      b0 + lA); async16(gB1,      b0 + lB);
  async16(gA0 + 32, a1 + lA); async16(gA1 + 32, a1 + lB);
  async16(gB0 + 32, b1 + lA); async16(gB1 + 32, b1 + lB);

  for (int kt = 0; kt < 31; ++kt) {
    asm volatile("s_waitcnt vmcnt(4)" ::: "memory");  // stage(kt) landed
    __builtin_amdgcn_s_barrier();                     // no vmcnt(0) drain
    if (kt < 30) {                                    // stage(kt+2)
      const int ko = (kt + 2) * 32;
      async16(gA0 + ko, a2 + lA); async16(gA1 + ko, a2 + lB);
      async16(gB0 + ko, b2 + lA); async16(gB1 + ko, b2 + lB);
    }
    bf16x8 af[4], bfr[4];
    #pragma unroll
    for (int i = 0; i < 4; ++i) {
      af[i]  = *(const bf16x8*)(a0 + aoff[i]);
      bfr[i] = *(const bf16x8*)(b0 + boff[i]);
    }
    #pragma unroll
    for (int mi = 0; mi < 4; ++mi)
      #pragma unroll
      for (int ni = 0; ni < 4; ++ni)
        acc[mi][ni] = __builtin_amdgcn_mfma_f32_16x16x32_bf16(af[mi], bfr[ni], acc[mi][ni], 0, 0, 0);
    // rotate: current <- next
    ushort* ta = a0; a0 = a1; a1 = a2; a2 = ta;
    ushort* tb = b0; b0 = b1; b1 = b2; b2 = tb;
  }
  // final iter (kt=31): only stage(31) outstanding
  asm volatile("s_waitcnt vmcnt(0)" ::: "memory");
  __builtin_amdgcn_s_barrier();
  {
    bf16x8 af[4], bfr[4];
    #pragma unroll
    for (int i = 0; i < 4; ++i) {
      af[i]  = *(const bf16x8*)(a0 + aoff[i]);
      bfr[i] = *(const bf16x8*)(b0 + boff[i]);
    }
    #pragma unroll
    for (int mi = 0; mi < 4; ++mi)
      #pragma unroll
      for (int ni = 0; ni < 4; ++ni)
        acc[mi][ni] = __builtin_amdgcn_mfma_f32_16x16x32_bf16(af[mi], bfr[ni], acc[mi][ni], 0, 0, 0);
  }

  // epilogue: bias + RoPE + scatter to Q/K (bf16)
  const int b = m0 >> 10;  // 128-tile never crosses a batch boundary
  const int baserow = m0 + wm * 64 + ((lane >> 4) << 2);
  #pragma unroll
  for (int ni = 0; ni < 4; ++ni) {
    const int n = n0 + wn * 64 + ni * 16 + (lane & 15);
    const float bv = bias[n];
    const int h  = n >> 7;
    const int c  = n & 127;
    const int d  = c & 63;
    const int pi = d >> 1;
    ushort* dst = ((c < 64) ? Qb : Kb) + (size_t)(b * NHEADS + h) * SEQ * 64 + d;
    #pragma unroll
    for (int mi = 0; mi < 4; ++mi) {
      #pragma unroll
      for (int j = 0; j < 4; ++j) {
        const int gm = baserow + mi * 16 + j;
        const int s  = gm & (SEQ - 1);
        float v = acc[mi][ni][j] + bv;
        float p = __shfl_xor(v, 1);  // paired channel (n^1) lives in lane^1
        float2 sc = ((const float2*)tab)[s * 32 + pi];
        float o = (d & 1) ? fmaf(v, sc.y, p * sc.x) : fmaf(v, sc.y, -p * sc.x);
        dst[(size_t)s * 64] = f2bf(o);
      }
    }
  }
}

// ---------------- output: all 64 tiles per bh (r10-proven) ----------------
__global__ __launch_bounds__(256) void k_out(
    const ushort* __restrict__ Qb, const ushort* __restrict__ Kb,
    const int* __restrict__ mask, float* __restrict__ out) {
  __shared__ __align__(16) ushort Qs[128 * 64];
  __shared__ __align__(16) ushort Ks[128 * 64];
  const int tid  = threadIdx.x;
  // XCD-aware remap (bijective: 6144 % 8 == 0; 768 wgid per XCD = 12 bh)
  const int orig = blockIdx.x;
  const int wgid = (orig & 7) * 768 + (orig >> 3);
  const int bh = wgid >> 6;              // 0..95
  const int b  = bh / NHEADS;
  const int mi_ = (wgid >> 3) & 7;
  const int ni_ = wgid & 7;
  const int m0 = mi_ * 128;
  const int n0 = ni_ * 128;
  const int* mb = mask + b * SEQ;
  float* ob = out + (size_t)bh * SEQ * SEQ;

  if (mi_ > ni_) {
    // ---- causal fill path: coalesced f32x4 nt streaming write ----
    const int c0 = (tid & 31) * 4;
    const int r0 = tid >> 5;
    f32x4 np4;
    #pragma unroll
    for (int j = 0; j < 4; ++j) np4[j] = mb[n0 + c0 + j] ? 0.0f : NEGV;
    for (int r = r0; r < 128; r += 8) {
      const int gm = m0 + r;
      const float mp = (mb[gm] ? 0.0f : NEGV) + NEGV;
      f32x4 v;
      #pragma unroll
      for (int j = 0; j < 4; ++j) v[j] = -(np4[j] + mp) * 0.125f;
      __builtin_nontemporal_store(v, (f32x4*)(ob + (size_t)gm * SEQ + n0 + c0));
    }
    return;
  }

  // ---- MFMA path (plain stores; r9: scalar nt stores are 2x slower) ----
  const int lane = tid & 63;
  const int wid  = tid >> 6;
  const int wm = wid >> 1, wn = wid & 1;
  const ushort* Qt = Qb + (size_t)bh * SEQ * 64;
  const ushort* Kt = Kb + (size_t)bh * SEQ * 64;

  #pragma unroll
  for (int is = 0; is < 4; ++is) {
    const int off = is * 4096 + tid * 16;
    const int row = off >> 7;
    const int g8  = ((((off >> 4) & 7) ^ (row & 7))) * 8;
    async16(Qt + (size_t)(m0 + row) * 64 + g8, Qs + is * 2048 + wid * 512);
    async16(Kt + (size_t)(n0 + row) * 64 + g8, Ks + is * 2048 + wid * 512);
  }
  __syncthreads();

  f32x4 acc[4][4] = {};
  const int kb = lane >> 4;
  #pragma unroll
  for (int ks = 0; ks < 2; ++ks) {
    bf16x8 qf[4], kf[4];
    #pragma unroll
    for (int i = 0; i < 4; ++i) {
      const int rq = wm * 64 + i * 16 + (lane & 15);
      qf[i] = *(const bf16x8*)(Qs + rq * 64 + ((ks * 4 + kb) ^ (rq & 7)) * 8);
      const int rk = wn * 64 + i * 16 + (lane & 15);
      kf[i] = *(const bf16x8*)(Ks + rk * 64 + ((ks * 4 + kb) ^ (rk & 7)) * 8);
    }
    #pragma unroll
    for (int mi = 0; mi < 4; ++mi)
      #pragma unroll
      for (int ni = 0; ni < 4; ++ni)
        acc[mi][ni] = __builtin_amdgcn_mfma_f32_16x16x32_bf16(qf[mi], kf[ni], acc[mi][ni], 0, 0, 0);
  }

  const int mrow0 = m0 + wm * 64 + ((lane >> 4) << 2);
  const int ncol0 = n0 + wn * 64 + (lane & 15);
  float npen[4];
  int gn_[4];
  #pragma unroll
  for (int ni = 0; ni < 4; ++ni) {
    gn_[ni]  = ncol0 + ni * 16;
    npen[ni] = mb[gn_[ni]] ? 0.0f : NEGV;
  }
  #pragma unroll
  for (int mi = 0; mi < 4; ++mi) {
    #pragma unroll
    for (int j = 0; j < 4; ++j) {
      const int gm = mrow0 + mi * 16 + j;
      const float mpen = mb[gm] ? 0.0f : NEGV;
      float* orow = ob + (size_t)gm * SEQ;
      #pragma unroll
      for (int ni = 0; ni < 4; ++ni) {
        const int gn = gn_[ni];
        const float tpen = (gm > gn) ? NEGV : 0.0f;
        orow[gn] = (acc[mi][ni][j] - (mpen + npen[ni] + tpen)) * 0.125f;
      }
    }
  }
}

// ---------------- launcher ----------------
extern "C" void kernel_launch(void* const* d_in, const int* in_sizes, int n_in,
                              void* d_out, int out_size, void* d_ws, size_t ws_size,
                              hipStream_t stream) {
  const float* inp  = (const float*)d_in[0];  // [8][1024][1024]
  const float* W    = (const float*)d_in[1];  // [1024][1536]
  const float* bias = (const float*)d_in[2];  // [1536]
  const int*   mask = (const int*)d_in[3];    // [8][1024]
  float* out = (float*)d_out;                 // [8][12][1024][1024]

  char* ws = (char*)d_ws;
  ushort* A16  = (ushort*)ws;                 // 16,777,216 B
  ushort* WT16 = (ushort*)(ws + 16777216);    //  3,145,728 B
  float*  tab  = (float*)(ws + 19922944);     //    262,144 B
  ushort* Qb   = (ushort*)(ws + 20185088);    // 12,582,912 B
  ushort* Kb   = (ushort*)(ws + 32768000);    // 12,582,912 B  (total ~45.4 MB)

  k_prep<<<2560, 256, 0, stream>>>(inp, W, A16, WT16, tab);
  k_gemm_proj<<<768, 256, 0, stream>>>(A16, WT16, bias, tab, Qb, Kb);
  k_out<<<6144, 256, 0, stream>>>(Qb, Kb, mask, out);
}